// Round 14
// baseline (28.199 us; speedup 1.0000x reference)
//
#include <hip/hip_runtime.h>
#include <cstddef>

#define NUM_TYPE 64
#define DD 256
#define NN 8192
#define GM128 128     // max type-aligned 128-row groups: 8192/128 + 64
#define LSTR 40       // LDS row stride (bf16 elems), +8 pad

typedef __bf16 bf16x8 __attribute__((ext_vector_type(8)));
typedef __bf16 bf16x4 __attribute__((ext_vector_type(4)));
typedef float f32x4 __attribute__((ext_vector_type(4)));

__device__ __forceinline__ bf16x4 cvt4(float4 v) {
  bf16x4 h;
  h[0] = (__bf16)v.x; h[1] = (__bf16)v.y; h[2] = (__bf16)v.z; h[3] = (__bf16)v.w;
  return h;
}

__device__ __forceinline__ float tanh_fast(float x) {
  float xc = fminf(fmaxf(x, -15.f), 15.f);
  float e = __expf(2.f * xc);
  return (e - 1.f) / (e + 1.f);
}

// --- Kernel 1: perm + type-aligned 128-row group table (parallel emit) ---
__global__ __launch_bounds__(1024) void build_perm128(
    const int* __restrict__ bi, int* __restrict__ type_off,
    int* __restrict__ perm, int* __restrict__ gtype, int* __restrict__ gfirst) {
  __shared__ int wcnt[16][NUM_TYPE];
  __shared__ int wbase[16][NUM_TYPE];
  __shared__ int cnt[NUM_TYPE];
  __shared__ int tstart[NUM_TYPE];
  __shared__ int gbase[NUM_TYPE];
  __shared__ int totals[2];
  const int tid = threadIdx.x;
  const int w = tid >> 6;
  for (int i = tid; i < 16 * NUM_TYPE; i += 1024) ((int*)wcnt)[i] = 0;
  __syncthreads();
  int myv[8];
#pragma unroll
  for (int rnd = 0; rnd < 8; ++rnd) {
    int v = bi[rnd * 1024 + tid];
    myv[rnd] = v;
    atomicAdd(&wcnt[w][v], 1);
  }
  __syncthreads();
  if (tid < NUM_TYPE) {
    int s = 0;
#pragma unroll
    for (int ww = 0; ww < 16; ++ww) { wbase[ww][tid] = s; s += wcnt[ww][tid]; }
    cnt[tid] = s;
  }
  __syncthreads();
  if (tid == 0) {
    int s = 0, p = 0;
    for (int t = 0; t < NUM_TYPE; ++t) {
      tstart[t] = s; gbase[t] = p;
      s += cnt[t];
      p += (cnt[t] + 127) >> 7;
    }
    totals[0] = s; totals[1] = p;
  }
  __syncthreads();
  if (tid < NUM_TYPE) {
    const int c = cnt[tid];
    const int ngr = (c + 127) >> 7;
    const int g0 = gbase[tid];
    const int s0 = tstart[tid];
    for (int j = 0; j < ngr; ++j) { gtype[g0 + j] = tid; gfirst[g0 + j] = s0 + j * 128; }
    type_off[tid] = s0;
#pragma unroll
    for (int ww = 0; ww < 16; ++ww) wbase[ww][tid] += s0;
  }
  if (tid == 0) type_off[NUM_TYPE] = totals[0];
  for (int g = totals[1] + tid; g < GM128; g += 1024) gtype[g] = -1;
  __syncthreads();
#pragma unroll
  for (int rnd = 0; rnd < 8; ++rnd) {
    int v = myv[rnd];
    int p = atomicAdd(&wbase[w][v], 1);
    perm[p] = rnd * 1024 + tid;
  }
}

// --- Kernel 2: blocked GEMM 128x128 tile, BK=32 double-buffered LDS ------
// grid 256 = 8 XCDs x 32; d -> l=(d&7)*32+(d>>3): contiguous (group,cb)
// runs per XCD. 8 waves: wave w -> rows (w>>1)*32..+32, cols (w&1)*64..+64.
__global__ __launch_bounds__(512) void gemm_tile(
    const float* __restrict__ desc,
    const float* __restrict__ layer1,
    const float* __restrict__ W,
    const float* __restrict__ bias,
    const int* __restrict__ type_off,
    const int* __restrict__ perm,
    const int* __restrict__ gtype,
    const int* __restrict__ gfirst,
    float* __restrict__ out) {
  const int d = blockIdx.x;
  const int l = (d & 7) * 32 + (d >> 3);
  const int g = l >> 1;
  const int cb = l & 1;
  const int t = gtype[g];
  if (t < 0) return;
  const int first = gfirst[g];
  const int limit = type_off[t + 1];

  const int tid = threadIdx.x;
  const int w = tid >> 6;
  const int lane = tid & 63;
  const int l15 = lane & 15;
  const int lg = lane >> 4;
  const int wr = w >> 1;          // 0..3: row quarter
  const int wc = w & 1;           // 0..1: col half

  __shared__ __bf16 At[2][128][LSTR];
  __shared__ __bf16 Bl[2][128][LSTR];
  __shared__ __bf16 Bw[2][128][LSTR];

  // staging: 4 threads/row, 8 floats (2 float4) each — full-line coalesced
  const int srow = tid >> 2;      // 0..127
  const int fseg = tid & 3;       // 0..3
  const int ar = first + srow;
  const int sA = (ar < limit) ? perm[ar] : -1;
  const float* aP  = desc + (size_t)(sA < 0 ? 0 : sA) * DD + fseg * 8;
  const int gcol = cb * 128 + srow;
  const float* blP = layer1 + ((size_t)t * DD + gcol) * DD + fseg * 8;
  const float* bwP = W + (size_t)gcol * DD + fseg * 8;

#define STAGE(buf, kb)                                                        \
  {                                                                           \
    float4 a0 = make_float4(0.f,0.f,0.f,0.f), a1 = a0;                        \
    if (sA >= 0) {                                                            \
      a0 = *reinterpret_cast<const float4*>(aP + (kb));                       \
      a1 = *reinterpret_cast<const float4*>(aP + (kb) + 4);                   \
    }                                                                         \
    float4 b0 = *reinterpret_cast<const float4*>(blP + (kb));                 \
    float4 b1 = *reinterpret_cast<const float4*>(blP + (kb) + 4);             \
    float4 w0 = *reinterpret_cast<const float4*>(bwP + (kb));                 \
    float4 w1 = *reinterpret_cast<const float4*>(bwP + (kb) + 4);             \
    *reinterpret_cast<bf16x4*>(&At[buf][srow][fseg * 8])     = cvt4(a0);      \
    *reinterpret_cast<bf16x4*>(&At[buf][srow][fseg * 8 + 4]) = cvt4(a1);      \
    *reinterpret_cast<bf16x4*>(&Bl[buf][srow][fseg * 8])     = cvt4(b0);      \
    *reinterpret_cast<bf16x4*>(&Bl[buf][srow][fseg * 8 + 4]) = cvt4(b1);      \
    *reinterpret_cast<bf16x4*>(&Bw[buf][srow][fseg * 8])     = cvt4(w0);      \
    *reinterpret_cast<bf16x4*>(&Bw[buf][srow][fseg * 8 + 4]) = cvt4(w1);      \
  }

  STAGE(0, 0)
  __syncthreads();

  f32x4 accL[2][4] = {};
  f32x4 accW[2][4] = {};
  int buf = 0;
#pragma unroll
  for (int kc = 0; kc < 8; ++kc) {
    if (kc < 7) STAGE(buf ^ 1, (kc + 1) * 32)
    bf16x8 af[2], bl[4], bw[4];
#pragma unroll
    for (int m = 0; m < 2; ++m)
      af[m] = *reinterpret_cast<const bf16x8*>(&At[buf][wr * 32 + m * 16 + l15][lg * 8]);
#pragma unroll
    for (int n = 0; n < 4; ++n) {
      bl[n] = *reinterpret_cast<const bf16x8*>(&Bl[buf][wc * 64 + n * 16 + l15][lg * 8]);
      bw[n] = *reinterpret_cast<const bf16x8*>(&Bw[buf][wc * 64 + n * 16 + l15][lg * 8]);
    }
#pragma unroll
    for (int m = 0; m < 2; ++m)
#pragma unroll
      for (int n = 0; n < 4; ++n) {
        accL[m][n] = __builtin_amdgcn_mfma_f32_16x16x32_bf16(af[m], bl[n], accL[m][n], 0, 0, 0);
        accW[m][n] = __builtin_amdgcn_mfma_f32_16x16x32_bf16(af[m], bw[n], accW[m][n], 0, 0, 0);
      }
    __syncthreads();
    buf ^= 1;
  }
#undef STAGE

  // epilogue: acc row = lg*4+i within 16-row frag, col = l15
  float bv[4];
#pragma unroll
  for (int n = 0; n < 4; ++n) bv[n] = bias[cb * 128 + wc * 64 + n * 16 + l15];
#pragma unroll
  for (int m = 0; m < 2; ++m) {
    const int orow = first + wr * 32 + m * 16 + l15;
    const int sOut = (orow < limit) ? perm[orow] : -1;
#pragma unroll
    for (int i = 0; i < 4; ++i) {
      const int sv = __shfl(sOut, lg * 4 + i, 64);
      if (sv >= 0) {
        float* op = out + (size_t)sv * DD + cb * 128 + wc * 64 + l15;
#pragma unroll
        for (int n = 0; n < 4; ++n)
          __builtin_nontemporal_store(tanh_fast(accL[m][n][i]) + accW[m][n][i] + bv[n],
                                      op + n * 16);
      }
    }
  }
}

extern "C" void kernel_launch(void* const* d_in, const int* in_sizes, int n_in,
                              void* d_out, int out_size, void* d_ws, size_t ws_size,
                              hipStream_t stream) {
  const int* bi       = (const int*)d_in[0];
  const float* desc   = (const float*)d_in[1];
  const float* layer1 = (const float*)d_in[2];
  const float* W      = (const float*)d_in[3];
  const float* bias   = (const float*)d_in[4];
  float* out = (float*)d_out;

  char* ws = (char*)d_ws;
  int* type_off = (int*)(ws);              // 65 ints   @ 0
  int* gtype    = (int*)(ws + 1024);       // 128 ints  @ 1 KB
  int* gfirst   = (int*)(ws + 4096);       // 128 ints  @ 4 KB
  int* perm     = (int*)(ws + 8192);       // 8192 ints @ 8 KB

  hipLaunchKernelGGL(build_perm128, dim3(1), dim3(1024), 0, stream,
                     bi, type_off, perm, gtype, gfirst);
  hipLaunchKernelGGL(gemm_tile, dim3(GM128 * 2), dim3(512), 0, stream,
                     desc, layer1, W, bias, type_off, perm, gtype, gfirst, out);
}

// Round 15
// 25.756 us; speedup vs baseline: 1.0948x; 1.0948x over previous
//
#include <hip/hip_runtime.h>
#include <cstddef>

#define NUM_TYPE 64
#define DD 256
#define NN 8192
#define GM64 192      // max type-aligned 64-row groups: 8192/64 + 64
#define LSTR 40       // LDS row stride (bf16 elems), +8 pad

typedef __bf16 bf16x8 __attribute__((ext_vector_type(8)));
typedef __bf16 bf16x4 __attribute__((ext_vector_type(4)));
typedef float f32x4 __attribute__((ext_vector_type(4)));

__device__ __forceinline__ bf16x4 cvt4(float4 v) {
  bf16x4 h;
  h[0] = (__bf16)v.x; h[1] = (__bf16)v.y; h[2] = (__bf16)v.z; h[3] = (__bf16)v.w;
  return h;
}

__device__ __forceinline__ float tanh_fast(float x) {
  float xc = fminf(fmaxf(x, -15.f), 15.f);
  float e = __expf(2.f * xc);
  return (e - 1.f) / (e + 1.f);
}

// --- Kernel 1: perm + type-aligned 64-row group table (parallel emit) ----
__global__ __launch_bounds__(1024) void build_perm64(
    const int* __restrict__ bi, int* __restrict__ type_off,
    int* __restrict__ perm, int* __restrict__ gtype, int* __restrict__ gfirst) {
  __shared__ int wcnt[16][NUM_TYPE];
  __shared__ int wbase[16][NUM_TYPE];
  __shared__ int cnt[NUM_TYPE];
  __shared__ int tstart[NUM_TYPE];
  __shared__ int gbase[NUM_TYPE];
  __shared__ int totals[2];
  const int tid = threadIdx.x;
  const int w = tid >> 6;
  for (int i = tid; i < 16 * NUM_TYPE; i += 1024) ((int*)wcnt)[i] = 0;
  __syncthreads();
  int myv[8];
#pragma unroll
  for (int rnd = 0; rnd < 8; ++rnd) {
    int v = bi[rnd * 1024 + tid];
    myv[rnd] = v;
    atomicAdd(&wcnt[w][v], 1);
  }
  __syncthreads();
  if (tid < NUM_TYPE) {
    int s = 0;
#pragma unroll
    for (int ww = 0; ww < 16; ++ww) { wbase[ww][tid] = s; s += wcnt[ww][tid]; }
    cnt[tid] = s;
  }
  __syncthreads();
  if (tid == 0) {
    int s = 0, p = 0;
    for (int t = 0; t < NUM_TYPE; ++t) {
      tstart[t] = s; gbase[t] = p;
      s += cnt[t];
      p += (cnt[t] + 63) >> 6;
    }
    totals[0] = s; totals[1] = p;
  }
  __syncthreads();
  if (tid < NUM_TYPE) {
    const int c = cnt[tid];
    const int ngr = (c + 63) >> 6;
    const int g0 = gbase[tid];
    const int s0 = tstart[tid];
    for (int j = 0; j < ngr; ++j) { gtype[g0 + j] = tid; gfirst[g0 + j] = s0 + j * 64; }
    type_off[tid] = s0;
#pragma unroll
    for (int ww = 0; ww < 16; ++ww) wbase[ww][tid] += s0;
  }
  if (tid == 0) type_off[NUM_TYPE] = totals[0];
  for (int g = totals[1] + tid; g < GM64; g += 1024) gtype[g] = -1;
  __syncthreads();
#pragma unroll
  for (int rnd = 0; rnd < 8; ++rnd) {
    int v = myv[rnd];
    int p = atomicAdd(&wbase[w][v], 1);
    perm[p] = rnd * 1024 + tid;
  }
}

// --- Kernel 2: blocked GEMM 64x64 tile, BK=32 double-buffered LDS --------
// grid 768 = 8 XCDs x 96; d -> l=(d&7)*96+(d>>3): contiguous (group,cb)
// runs per XCD. 4 waves: wave w -> rows (w>>1)*32..+32, cols (w&1)*32..+32.
__global__ __launch_bounds__(256) void gemm_tile(
    const float* __restrict__ desc,
    const float* __restrict__ layer1,
    const float* __restrict__ W,
    const float* __restrict__ bias,
    const int* __restrict__ type_off,
    const int* __restrict__ perm,
    const int* __restrict__ gtype,
    const int* __restrict__ gfirst,
    float* __restrict__ out) {
  const int d = blockIdx.x;
  const int l = (d & 7) * 96 + (d >> 3);
  const int g = l >> 2;
  const int cb = l & 3;
  const int t = gtype[g];
  if (t < 0) return;
  const int first = gfirst[g];
  const int limit = type_off[t + 1];

  const int tid = threadIdx.x;
  const int w = tid >> 6;
  const int lane = tid & 63;
  const int l15 = lane & 15;
  const int lg = lane >> 4;
  const int wr = w >> 1;          // 0..1: row half
  const int wc = w & 1;           // 0..1: col half

  __shared__ __bf16 At[2][64][LSTR];
  __shared__ __bf16 Bl[2][64][LSTR];
  __shared__ __bf16 Bw[2][64][LSTR];

  // staging: 4 threads/row, 8 floats (2 float4) each — coalesced 128B rows
  const int srow = tid >> 2;      // 0..63
  const int fseg = tid & 3;       // 0..3
  const int ar = first + srow;
  const int sA = (ar < limit) ? perm[ar] : -1;
  const float* aP  = desc + (size_t)(sA < 0 ? 0 : sA) * DD + fseg * 8;
  const int gcol = cb * 64 + srow;
  const float* blP = layer1 + ((size_t)t * DD + gcol) * DD + fseg * 8;
  const float* bwP = W + (size_t)gcol * DD + fseg * 8;

#define STAGE(buf, kb)                                                        \
  {                                                                           \
    float4 a0 = make_float4(0.f,0.f,0.f,0.f), a1 = a0;                        \
    if (sA >= 0) {                                                            \
      a0 = *reinterpret_cast<const float4*>(aP + (kb));                       \
      a1 = *reinterpret_cast<const float4*>(aP + (kb) + 4);                   \
    }                                                                         \
    float4 b0 = *reinterpret_cast<const float4*>(blP + (kb));                 \
    float4 b1 = *reinterpret_cast<const float4*>(blP + (kb) + 4);             \
    float4 w0 = *reinterpret_cast<const float4*>(bwP + (kb));                 \
    float4 w1 = *reinterpret_cast<const float4*>(bwP + (kb) + 4);             \
    *reinterpret_cast<bf16x4*>(&At[buf][srow][fseg * 8])     = cvt4(a0);      \
    *reinterpret_cast<bf16x4*>(&At[buf][srow][fseg * 8 + 4]) = cvt4(a1);      \
    *reinterpret_cast<bf16x4*>(&Bl[buf][srow][fseg * 8])     = cvt4(b0);      \
    *reinterpret_cast<bf16x4*>(&Bl[buf][srow][fseg * 8 + 4]) = cvt4(b1);      \
    *reinterpret_cast<bf16x4*>(&Bw[buf][srow][fseg * 8])     = cvt4(w0);      \
    *reinterpret_cast<bf16x4*>(&Bw[buf][srow][fseg * 8 + 4]) = cvt4(w1);      \
  }

  STAGE(0, 0)
  __syncthreads();

  f32x4 accL[2][2] = {};
  f32x4 accW[2][2] = {};
  int buf = 0;
#pragma unroll
  for (int kc = 0; kc < 8; ++kc) {
    if (kc < 7) STAGE(buf ^ 1, (kc + 1) * 32)
    bf16x8 af[2], bl[2], bw[2];
#pragma unroll
    for (int m = 0; m < 2; ++m)
      af[m] = *reinterpret_cast<const bf16x8*>(&At[buf][wr * 32 + m * 16 + l15][lg * 8]);
#pragma unroll
    for (int n = 0; n < 2; ++n) {
      bl[n] = *reinterpret_cast<const bf16x8*>(&Bl[buf][wc * 32 + n * 16 + l15][lg * 8]);
      bw[n] = *reinterpret_cast<const bf16x8*>(&Bw[buf][wc * 32 + n * 16 + l15][lg * 8]);
    }
#pragma unroll
    for (int m = 0; m < 2; ++m)
#pragma unroll
      for (int n = 0; n < 2; ++n) {
        accL[m][n] = __builtin_amdgcn_mfma_f32_16x16x32_bf16(af[m], bl[n], accL[m][n], 0, 0, 0);
        accW[m][n] = __builtin_amdgcn_mfma_f32_16x16x32_bf16(af[m], bw[n], accW[m][n], 0, 0, 0);
      }
    __syncthreads();
    buf ^= 1;
  }
#undef STAGE

  // epilogue: acc row = lg*4+i within 16-row frag, col = l15
#pragma unroll
  for (int m = 0; m < 2; ++m) {
    const int orow = first + wr * 32 + m * 16 + l15;
    const int sOut = (orow < limit) ? perm[orow] : -1;
#pragma unroll
    for (int i = 0; i < 4; ++i) {
      const int sv = __shfl(sOut, lg * 4 + i, 64);
      if (sv >= 0) {
        float* op = out + (size_t)sv * DD + cb * 64 + wc * 32 + l15;
#pragma unroll
        for (int n = 0; n < 2; ++n) {
          const float bv = bias[cb * 64 + wc * 32 + n * 16 + l15];
          __builtin_nontemporal_store(tanh_fast(accL[m][n][i]) + accW[m][n][i] + bv,
                                      op + n * 16);
        }
      }
    }
  }
}

extern "C" void kernel_launch(void* const* d_in, const int* in_sizes, int n_in,
                              void* d_out, int out_size, void* d_ws, size_t ws_size,
                              hipStream_t stream) {
  const int* bi       = (const int*)d_in[0];
  const float* desc   = (const float*)d_in[1];
  const float* layer1 = (const float*)d_in[2];
  const float* W      = (const float*)d_in[3];
  const float* bias   = (const float*)d_in[4];
  float* out = (float*)d_out;

  char* ws = (char*)d_ws;
  int* type_off = (int*)(ws);              // 65 ints   @ 0
  int* gtype    = (int*)(ws + 1024);       // 192 ints  @ 1 KB
  int* gfirst   = (int*)(ws + 4096);       // 192 ints  @ 4 KB
  int* perm     = (int*)(ws + 8192);       // 8192 ints @ 8 KB

  hipLaunchKernelGGL(build_perm64, dim3(1), dim3(1024), 0, stream,
                     bi, type_off, perm, gtype, gfirst);
  hipLaunchKernelGGL(gemm_tile, dim3(GM64 * 4), dim3(256), 0, stream,
                     desc, layer1, W, bias, type_off, perm, gtype, gfirst, out);
}